// Round 1
// baseline (250.442 us; speedup 1.0000x reference)
//
#include <hip/hip_runtime.h>

#define GH 721
#define GW 1440
#define NLVL 8

// One thread per point. Unrolled over the 8 pyramid levels.
// inv_res = 1/(0.25 * 2^l) = 4 * 2^-l : exact powers of two, so
// multiply-by-reciprocal is bit-identical to the reference's division.
__global__ __launch_bounds__(256) void coolchic_interp_kernel(
    const float* __restrict__ x,
    const float* __restrict__ emb,
    float* __restrict__ out,
    int n)
{
    int i = blockIdx.x * blockDim.x + threadIdx.x;
    if (i >= n) return;

    float2 p = reinterpret_cast<const float2*>(x)[i];
    float lat = p.x;
    float lon = p.y;
    float lat_num = 90.0f - lat;   // numerator for lat index (>= 0)

    float o[NLVL];
    float inv = 4.0f;              // 1 / 0.25

    #pragma unroll
    for (int l = 0; l < NLVL; ++l) {
        float latf = lat_num * inv;
        float lonf = lon * inv;
        // values are non-negative -> int truncation == floor
        int la = (int)latf;
        int lo = (int)lonf;
        int laf = min(la, GH - 1);
        int lof = min(lo, GW - 1);
        int lac = min(la + 1, GH - 1);
        int loc = min(lo + 1, GW - 1);
        // fractions use CLAMPED floor indices (matches reference)
        float fr_la = latf - (float)laf;
        float fr_lo = lonf - (float)lof;

        const float* g = emb + (size_t)l * (GH * GW);
        float vff = g[laf * GW + lof];
        float vfc = g[laf * GW + loc];
        float vcf = g[lac * GW + lof];
        float vcc = g[lac * GW + loc];

        float vf = vff + fr_lo * (vfc - vff);
        float vc = vcf + fr_lo * (vcc - vcf);
        o[l] = vf + fr_la * (vc - vf);

        inv *= 0.5f;
    }

    float4* o4 = reinterpret_cast<float4*>(out + (size_t)i * NLVL);
    o4[0] = make_float4(o[0], o[1], o[2], o[3]);
    o4[1] = make_float4(o[4], o[5], o[6], o[7]);
}

extern "C" void kernel_launch(void* const* d_in, const int* in_sizes, int n_in,
                              void* d_out, int out_size, void* d_ws, size_t ws_size,
                              hipStream_t stream) {
    const float* x   = (const float*)d_in[0];   // [N, 2]
    const float* emb = (const float*)d_in[1];   // [8, 721, 1440]
    float* out = (float*)d_out;                 // [N, 8]
    int n = in_sizes[0] / 2;

    int block = 256;
    int grid = (n + block - 1) / block;
    coolchic_interp_kernel<<<grid, block, 0, stream>>>(x, emb, out, n);
}

// Round 3
// 189.021 us; speedup vs baseline: 1.3249x; 1.3249x over previous
//
#include <hip/hip_runtime.h>

#define GH 721
#define GW 1440
#define NLVL 8

typedef float vf2 __attribute__((ext_vector_type(2)));
typedef float vf4 __attribute__((ext_vector_type(4)));

// One thread per point, all 8 pyramid levels unrolled.
// Phase 1: compute all addresses, issue all 16 gather loads (paired columns
//          as unaligned float2 -> one global_load_dwordx2 per row probe).
// Phase 2: arithmetic + coalesced float4 stores.
// inv = 1/(0.25*2^l) is an exact power of two -> mul == reference's division.
__global__ __launch_bounds__(256) void coolchic_interp_kernel(
    const float* __restrict__ x,
    const float* __restrict__ emb,
    float* __restrict__ out,
    int n)
{
    int i = blockIdx.x * blockDim.x + threadIdx.x;
    if (i >= n) return;

    vf2 p = __builtin_nontemporal_load(reinterpret_cast<const vf2*>(x) + i);
    float lat_num = 90.0f - p.x;   // >= 0
    float lon     = p.y;           // [0, 360)

    vf2   pf[NLVL];   // (g[laf][c], g[laf][c+1])
    vf2   pc[NLVL];   // (g[lac][c], g[lac][c+1])
    float fla[NLVL], flo[NLVL];
    int   edge[NLVL];

    float inv = 4.0f;
    #pragma unroll
    for (int l = 0; l < NLVL; ++l) {
        float latf = lat_num * inv;
        float lonf = lon * inv;
        int la = (int)latf;          // >=0 -> trunc == floor
        int lo = (int)lonf;          // lo <= GW-1 always (lon < 360)
        int laf = min(la,     GH - 1);
        int lac = min(la + 1, GH - 1);
        int c   = min(lo,     GW - 2);   // pair (c, c+1) always in-bounds
        // fractions use CLAMPED floor indices (reference quirk); lof==lo here
        fla[l]  = latf - (float)laf;
        flo[l]  = lonf - (float)lo;
        edge[l] = (lo > GW - 2);

        const float* g = emb + (size_t)l * (GH * GW);
        pf[l] = *reinterpret_cast<const vf2*>(g + laf * GW + c);
        pc[l] = *reinterpret_cast<const vf2*>(g + lac * GW + c);
        inv *= 0.5f;
    }

    float o[NLVL];
    #pragma unroll
    for (int l = 0; l < NLVL; ++l) {
        float vff = edge[l] ? pf[l].y : pf[l].x;
        float vfc = pf[l].y;
        float vcf = edge[l] ? pc[l].y : pc[l].x;
        float vcc = pc[l].y;
        float vf = vff + flo[l] * (vfc - vff);
        float vc = vcf + flo[l] * (vcc - vcf);
        o[l] = vf + fla[l] * (vc - vf);
    }

    vf4* o4 = reinterpret_cast<vf4*>(out + (size_t)i * NLVL);
    vf4 o_lo = { o[0], o[1], o[2], o[3] };
    vf4 o_hi = { o[4], o[5], o[6], o[7] };
    __builtin_nontemporal_store(o_lo, o4);
    __builtin_nontemporal_store(o_hi, o4 + 1);
}

extern "C" void kernel_launch(void* const* d_in, const int* in_sizes, int n_in,
                              void* d_out, int out_size, void* d_ws, size_t ws_size,
                              hipStream_t stream) {
    const float* x   = (const float*)d_in[0];   // [N, 2]
    const float* emb = (const float*)d_in[1];   // [8, 721, 1440]
    float* out = (float*)d_out;                 // [N, 8]
    int n = in_sizes[0] / 2;

    int block = 256;
    int grid = (n + block - 1) / block;
    coolchic_interp_kernel<<<grid, block, 0, stream>>>(x, emb, out, n);
}